// Round 9
// baseline (534.274 us; speedup 1.0000x reference)
//
#include <hip/hip_runtime.h>
#include <math.h>
#include <float.h>
#include <limits.h>
#include <stdint.h>

namespace {

constexpr int B  = 2;
constexpr int CK = 64;
constexpr int N  = 12960;   // T*H*W
constexpr int M  = 1620;    // H*W
constexpr int CV = 384;
constexpr int K  = 20;

constexpr int MT     = 16;                    // m per phase-1 block
constexpr int SEG    = 1024;                  // n per segment (LDS-resident)
constexpr int NSEG   = (N + SEG - 1) / SEG;   // 13 (last segment = 672)
constexpr int MTILES = (M + MT - 1) / MT;     // 102
constexpr int AP     = SEG + 4;               // affL row pad (bank skew)

// strict lexicographic "better": value desc, index asc (lax.top_k tie order)
__device__ __forceinline__ bool lex_gt(float av, int an, float bv, int bn) {
  return (av > bv) || (av == bv && an < bn);
}

// [C][N] -> [N][C] transpose
__global__ __launch_bounds__(256) void transpose_in_kernel(const float* __restrict__ src,
                                                           float* __restrict__ dst, int C) {
  __shared__ float tile[64][65];
  int b = blockIdx.z;
  int n0 = blockIdx.x * 64;
  int c0 = blockIdx.y * 64;
  int tx = threadIdx.x & 63, ty = threadIdx.x >> 6;
  for (int r = ty; r < 64; r += 4) {
    int c = c0 + r, n = n0 + tx;
    tile[r][tx] = (n < N) ? src[((size_t)b * C + c) * N + n] : 0.f;
  }
  __syncthreads();
  for (int r = ty; r < 64; r += 4) {
    int n = n0 + r, c = c0 + tx;
    if (n < N) dst[((size_t)b * N + n) * C + c] = tile[tx][r];
  }
}

// out[b][c][m] = outT[b][m][c]
__global__ __launch_bounds__(256) void transpose_out_kernel(const float* __restrict__ outT,
                                                            float* __restrict__ out) {
  __shared__ float tile[64][65];
  int b = blockIdx.z;
  int m0 = blockIdx.x * 64;
  int c0 = blockIdx.y * 64;
  int tx = threadIdx.x & 63, ty = threadIdx.x >> 6;
  for (int r = ty; r < 64; r += 4) {
    int m = m0 + r;
    if (m < M) tile[r][tx] = outT[((size_t)b * M + m) * CV + c0 + tx];
  }
  __syncthreads();
  for (int r = ty; r < 64; r += 4) {
    int c = c0 + r, m = m0 + tx;
    if (m < M) out[((size_t)b * CV + c) * M + m] = tile[tx][r];
  }
}

// a_sq[b,n] = sum_c mk[b,c,n]^2
__global__ __launch_bounds__(256) void asq_kernel(const float* __restrict__ mk,
                                                  float* __restrict__ asq) {
  int i = blockIdx.x * 256 + threadIdx.x;
  if (i >= B * N) return;
  int b = i / N, n = i - b * N;
  const float* p = mk + (size_t)b * CK * N + n;
  float s = 0.f;
#pragma unroll
  for (int c = 0; c < CK; ++c) {
    float v = p[(size_t)c * N];
    s += v * v;
  }
  asq[i] = s;
}

// Phase 1: one block per (b, 16-m tile, 1024-n segment).
// GEMM (16m x 1024n, zero-redundancy mk loads) -> LDS tile -> per-m exact
// sorted top-20 via per-lane bitonic-16 + 20-round shfl head-merge
// (field-verified in R8's bootstrap). No atomics, no histograms.
// Affinity FMA chain identical to all passing rounds -> identical selection.
__global__ __launch_bounds__(512, 2) void vos_seg_kernel(
    const float* __restrict__ mk, const float* __restrict__ qk,
    const float* __restrict__ asq, float* __restrict__ gcv,
    int* __restrict__ gci) {
  const int b = blockIdx.z, sg = blockIdx.y;
  const int mbase = blockIdx.x * MT;
  const int t = threadIdx.x;
  const int n0 = sg * SEG;
  const int segLen = min(SEG, N - n0);

  __shared__ float affL[MT][AP];     // 65.8 KB
  __shared__ float qs[CK][MT + 4];   // 5.1 KB  (row 80 B, 16B-aligned)

  // stage qk tile
  for (int l = t; l < CK * MT; l += 512) {
    int c = l >> 4, ml = l & 15;
    int mg = mbase + ml;
    qs[c][ml] = (mg < M) ? qk[((size_t)b * CK + c) * M + mg] : 0.f;
  }
  __syncthreads();

  // ---- GEMM: thread = (g = t&255 -> 4 consecutive n, h = t>>8 -> 8 m) ----
  {
    const int g = t & 255, h = t >> 8;
    const int mh = h * 8;
    const int nl = 4 * g;
    if (nl < segLen) {   // segLen % 4 == 0 -> all-or-nothing per float4
      const float* mkb = mk + (size_t)b * CK * N + n0 + nl;
      float4 acc[8];
#pragma unroll
      for (int j = 0; j < 8; ++j) acc[j] = make_float4(0.f, 0.f, 0.f, 0.f);
#pragma unroll 4
      for (int c = 0; c < CK; ++c) {
        const float4 kv = *reinterpret_cast<const float4*>(mkb + (size_t)c * N);
        const float4 qa = *reinterpret_cast<const float4*>(&qs[c][mh]);
        const float4 qb = *reinterpret_cast<const float4*>(&qs[c][mh + 4]);
        const float qv[8] = {qa.x, qa.y, qa.z, qa.w, qb.x, qb.y, qb.z, qb.w};
#pragma unroll
        for (int j = 0; j < 8; ++j) {
          acc[j].x += kv.x * qv[j];
          acc[j].y += kv.y * qv[j];
          acc[j].z += kv.z * qv[j];
          acc[j].w += kv.w * qv[j];
        }
      }
      const float4 sq = *reinterpret_cast<const float4*>(asq + (size_t)b * N + n0 + nl);
#pragma unroll
      for (int j = 0; j < 8; ++j) {
        float4 r;
        r.x = (2.f * acc[j].x - sq.x) * 0.125f;
        r.y = (2.f * acc[j].y - sq.y) * 0.125f;
        r.z = (2.f * acc[j].z - sq.z) * 0.125f;
        r.w = (2.f * acc[j].w - sq.w) * 0.125f;
        *reinterpret_cast<float4*>(&affL[mh + j][nl]) = r;
      }
    } else {   // pad columns: below every real affinity
      const float4 z = make_float4(-FLT_MAX, -FLT_MAX, -FLT_MAX, -FLT_MAX);
#pragma unroll
      for (int j = 0; j < 8; ++j)
        *reinterpret_cast<float4*>(&affL[mh + j][nl]) = z;
    }
  }
  __syncthreads();

  // ---- selection: 2 passes x (8 m, 64 lanes/m, 16 values/lane) ----
  const int s = t & 63;
#pragma unroll 1
  for (int pass = 0; pass < 2; ++pass) {
    const int m_ = (t >> 6) + 8 * pass;
    float v[16]; int nn[16];
#pragma unroll
    for (int j = 0; j < 16; ++j) {
      int nloc = s + 64 * j;
      v[j] = affL[m_][nloc];
      nn[j] = n0 + nloc;   // pads (last seg) carry v=-FLT_MAX, unique large n
    }
    // per-lane bitonic sort, best-first (lexicographic) — R8-verified network
#pragma unroll
    for (int kk = 2; kk <= 16; kk <<= 1)
#pragma unroll
      for (int jj = kk >> 1; jj > 0; jj >>= 1)
#pragma unroll
        for (int i = 0; i < 16; ++i) {
          int l2 = i ^ jj;
          if (l2 > i) {
            bool up = ((i & kk) == 0);
            bool sw_ = up ? lex_gt(v[l2], nn[l2], v[i], nn[i])
                          : lex_gt(v[i], nn[i], v[l2], nn[l2]);
            if (sw_) {
              float tv_ = v[i]; v[i] = v[l2]; v[l2] = tv_;
              int tn_ = nn[i]; nn[i] = nn[l2]; nn[l2] = tn_;
            }
          }
        }
    // 20-round merge across 64 lanes (heads of sorted lists)
    const int mg = mbase + m_;
    const size_t obase = (((size_t)b * M + (size_t)mg) * NSEG + sg) * (size_t)K;
    float hv = v[0]; int hn = nn[0];
    for (int r = 0; r < K; ++r) {
      float bv = hv; int bn = hn;
#pragma unroll
      for (int off = 32; off >= 1; off >>= 1) {
        float ov = __shfl_xor(bv, off);
        int on = __shfl_xor(bn, off);
        if (lex_gt(ov, on, bv, bn)) { bv = ov; bn = on; }
      }
      if (s == 0 && mg < M) { gcv[obase + r] = bv; gci[obase + r] = bn; }
      if (bn == hn) {   // winner (unique n): advance my sorted list
#pragma unroll
        for (int i = 0; i < 15; ++i) { v[i] = v[i + 1]; nn[i] = nn[i + 1]; }
        v[15] = -FLT_MAX; nn[15] = INT_MAX;
        hv = v[0]; hn = nn[0];
      }
    }
  }
}

// Phase 2: merge 13 sorted per-segment lists -> exact global top-20
// (v desc, n asc) -> softmax -> fused mvT gather -> outT[b][m][c].
// (R6 field-verified logic, NSEG 26 -> 13.)
__global__ __launch_bounds__(128) void merge_softmax_gather_kernel(
    const float* __restrict__ gcv, const int* __restrict__ gci,
    const float* __restrict__ mvT, float* __restrict__ outT) {
  const int m = blockIdx.x, b = blockIdx.y, t = threadIdx.x;
  __shared__ float lv[NSEG * K];
  __shared__ int   li[NSEG * K];
  __shared__ float wv[K];
  __shared__ int   wn[K];
  __shared__ float sw[K];
  const size_t base = ((size_t)b * M + m) * (size_t)(NSEG * K);
  for (int l = t; l < NSEG * K; l += 128) { lv[l] = gcv[base + l]; li[l] = gci[base + l]; }
  __syncthreads();

  if (t < 64) {
    const bool act = t < NSEG;
    int pos = 0;
    float hv = act ? lv[t * K] : -FLT_MAX;
    int   hn = act ? li[t * K] : INT_MAX;
    for (int r = 0; r < K; ++r) {
      float bv = hv; int bn = hn;
#pragma unroll
      for (int off = 16; off >= 1; off >>= 1) {
        float ov = __shfl_xor(bv, off);
        int on = __shfl_xor(bn, off);
        if (lex_gt(ov, on, bv, bn)) { bv = ov; bn = on; }
      }
      if (t == 0) { wv[r] = bv; wn[r] = bn; }
      if (act && bn == hn) {
        ++pos;
        hv = (pos < K) ? lv[t * K + pos] : -FLT_MAX;
        hn = (pos < K) ? li[t * K + pos] : INT_MAX;
      }
    }
    // softmax over the 20 winners
    float v = (t < K) ? wv[t] : -FLT_MAX;
    float mx = v;
#pragma unroll
    for (int off = 1; off < 64; off <<= 1) mx = fmaxf(mx, __shfl_xor(mx, off));
    float e = (t < K) ? expf(v - mx) : 0.f;
    float ss = e;
#pragma unroll
    for (int off = 1; off < 64; off <<= 1) ss += __shfl_xor(ss, off);
    if (t < K) sw[t] = e / ss;
  }
  __syncthreads();

  if (t < CV / 4) {
    const float4* tb4 = reinterpret_cast<const float4*>(mvT + (size_t)b * N * CV);
    float4 acc = make_float4(0.f, 0.f, 0.f, 0.f);
#pragma unroll
    for (int j = 0; j < K; ++j) {
      const float wj = sw[j];
      const float4 v = tb4[(size_t)wn[j] * (CV / 4) + t];
      acc.x += wj * v.x; acc.y += wj * v.y; acc.z += wj * v.z; acc.w += wj * v.w;
    }
    reinterpret_cast<float4*>(outT + ((size_t)b * M + m) * CV)[t] = acc;
  }
}

}  // namespace

extern "C" void kernel_launch(void* const* d_in, const int* in_sizes, int n_in,
                              void* d_out, int out_size, void* d_ws, size_t ws_size,
                              hipStream_t stream) {
  const float* mk = (const float*)d_in[0];
  const float* qk = (const float*)d_in[1];
  const float* mv = (const float*)d_in[2];
  float* out = (float*)d_out;

  char* w = (char*)d_ws;
  float* asq = (float*)w;
  size_t o = (size_t)B * N * sizeof(float);              // 103,680 B
  float* mvT = (float*)(w + o);
  o += (size_t)B * N * CV * sizeof(float);               // +39,813,120 B
  float* outT = (float*)(w + o);
  o += (size_t)B * M * CV * sizeof(float);               // +4,976,640 B
  float* gcv = (float*)(w + o);
  o += (size_t)B * M * NSEG * K * sizeof(float);         // +3,369,600 B
  int* gci = (int*)(w + o);
  o += (size_t)B * M * NSEG * K * sizeof(int);           // +3,369,600 B (~51.6 MB)

  transpose_in_kernel<<<dim3((N + 63) / 64, CV / 64, B), 256, 0, stream>>>(mv, mvT, CV);
  asq_kernel<<<(B * N + 255) / 256, 256, 0, stream>>>(mk, asq);

  vos_seg_kernel<<<dim3(MTILES, NSEG, B), 512, 0, stream>>>(mk, qk, asq, gcv, gci);
  merge_softmax_gather_kernel<<<dim3(M, B), 128, 0, stream>>>(gcv, gci, mvT, outT);

  transpose_out_kernel<<<dim3((M + 63) / 64, CV / 64, B), 256, 0, stream>>>(outT, out);
}